// Round 1
// baseline (339.636 us; speedup 1.0000x reference)
//
#include <hip/hip_runtime.h>

typedef unsigned int   u32;
typedef unsigned short u16;

typedef _Float16 h2  __attribute__((ext_vector_type(2)));
typedef _Float16 h8  __attribute__((ext_vector_type(8)));
typedef float    f32x4 __attribute__((ext_vector_type(4)));

#define M_TOK 128

__device__ __forceinline__ u16 f2h_(float f) {
    _Float16 h = (_Float16)f; return __builtin_bit_cast(u16, h);
}
__device__ __forceinline__ float h2f_(u16 b) {
    _Float16 h = __builtin_bit_cast(_Float16, b); return (float)h;
}
__device__ __forceinline__ void acc8(uint4 v, float* s) {
#pragma unroll
    for (int i = 0; i < 4; ++i) {
        u32 w = ((const u32*)&v)[i];
        s[2 * i]     += h2f_((u16)(w & 0xFFFF));
        s[2 * i + 1] += h2f_((u16)(w >> 16));
    }
}

// AWQ nibble order: n&7 = j sits at bit position SH[j]
__constant__ int SHC[8] = {0, 16, 4, 20, 8, 24, 12, 28};

// ---------------------------------------------------------------------------
// pack_zs: (qz, sc) -> zs[g][n] u32 { lo16: fp16(-(1024+z)), hi16: fp16(sc) }
// ---------------------------------------------------------------------------
__launch_bounds__(256)
__global__ void pack_zs(const int* __restrict__ qz, const float* __restrict__ sc,
                        u32* __restrict__ zs, int qws, int scs, int Ncols, int total) {
    const int idx = blockIdx.x * 256 + threadIdx.x;
    if (idx >= total) return;
    const int g = idx / Ncols, n = idx - g * Ncols;
    const u32 d = (u32)qz[(size_t)g * qws + (n >> 3)];
    const u32 zj = (d >> SHC[n & 7]) & 15u;
    const u32 mz = 0xE400u | zj;                    // fp16 -(1024+z)
    const u16 sh = f2h_(sc[(size_t)g * scs + n]);
    zs[(size_t)g * Ncols + n] = mz | ((u32)sh << 16);
}

// A-fragment-major layout: elem offset for logical (m, k):
//   kb=k/32, q=(k/8)&3, j=k&7, mt=m/16, l16=m&15
//   off = ((kb*8+mt)*64 + q*16 + l16)*8 + j    (fp16 elements)

// ---------------------------------------------------------------------------
// RMSNorm: one block per token row, fp32 in -> fp16 out in Afrag layout
// ---------------------------------------------------------------------------
__launch_bounds__(256)
__global__ void rmsnorm_k(const float* __restrict__ in, const float* __restrict__ w,
                          u16* __restrict__ out) {
    const int row = blockIdx.x;
    const float* x = in + (size_t)row * 4096;
    float ss = 0.f;
#pragma unroll
    for (int j = 0; j < 16; ++j) {
        float v = x[threadIdx.x + 256 * j];
        ss += v * v;
    }
#pragma unroll
    for (int off = 32; off > 0; off >>= 1) ss += __shfl_down(ss, off, 64);
    __shared__ float ws4[4];
    if ((threadIdx.x & 63) == 0) ws4[threadIdx.x >> 6] = ss;
    __syncthreads();
    float total = ws4[0] + ws4[1] + ws4[2] + ws4[3];
    float r = rsqrtf(total * (1.f / 4096.f) + 1e-6f);
    const int mt = row >> 4, l16 = row & 15;
#pragma unroll
    for (int c2 = 0; c2 < 2; ++c2) {
        int c = threadIdx.x * 2 + c2;
        int kb = c >> 2, qq = c & 3;
        u16 o8[8];
#pragma unroll
        for (int j = 0; j < 8; ++j) {
            int i = c * 8 + j;
            o8[j] = f2h_(x[i] * r * w[i]);
        }
        *(uint4*)(out + ((size_t)(kb * 8 + mt) * 64 + qq * 16 + l16) * 8) = *(const uint4*)o8;
    }
}

// ---------------------------------------------------------------------------
// AWQ GEMM, barrier-free, occupancy-optimized.
// Wave tile: 64m x 32n. Block: 4 waves = 2 m-halves x 2 n-halves -> 128m x 64n.
// The two m-half waves of an n-half redundantly dequant the same 32n strip
// (private LDS, no barriers) — trades ~2x dequant VALU (17% busy -> ~30%)
// for A-frag regs 128->32 and acc 64->32: ~150 unified regs -> 3 waves/SIMD
// (vs 192 -> 2 before). Grid.x doubled (64-wide n tiles) to feed 3 blocks/CU.
// A single-buffered: issued at step start, consumed by MFMA at step end
// (A is L1/L2-resident; intra-step distance covers the hit latency).
// qw raw prefetch distance = 1 full 64k-step (thousands of cycles).
// ---------------------------------------------------------------------------
__launch_bounds__(256, 3)
__global__ void gemm_awq(const u16* __restrict__ A, const u32* __restrict__ zs,
                         const int* __restrict__ qw, u16* __restrict__ part,
                         int qws, int N, int K, int kchunk) {
    __shared__ __align__(16) char ldsB[4 * 4608];   // per-wave 32 rows x 144 B

    const int tid = threadIdx.x, w = tid >> 6, lane = tid & 63;
    const int q = lane >> 4, l16 = lane & 15;
    const int mh = w >> 1;                           // m-half: rows [mh*64, mh*64+64)
    const int n0w = blockIdx.x * 64 + (w & 1) * 32;  // 32n strip of this wave
    const int pc0 = n0w >> 3;
    const int kp = lane & 31, h = lane >> 5;
    const int sk = blockIdx.y, kc0 = sk * kchunk, kend = min(kc0 + kchunk, K);

    char* myB   = ldsB + w * 4608;
    char* wbase = myB + kp * 4;
    const u16* Ala = A + lane * 8;
    const int* qws_base = qw + pc0;
    const u32* zsA = zs + n0w + h * 8;
    const u32* zsB = zs + n0w + 16 + h * 8;

    f32x4 acc[4][2] = {};
    uint4 za0, za1, zb0, zb1;       // current group's packed (mz, sc)

    auto ldraw = [&](int k0) -> uint4 {
        return *(const uint4*)(qws_base + (size_t)(k0 + lane) * qws);
    };
    auto loadzs = [&](int g) {
        za0 = *(const uint4*)(zsA + (size_t)g * N);
        za1 = *(const uint4*)(zsA + (size_t)g * N + 4);
        zb0 = *(const uint4*)(zsB + (size_t)g * N);
        zb1 = *(const uint4*)(zsB + (size_t)g * N + 4);
    };
    auto route = [&](uint4 rv, u32* d) {
        const int i0 = kp * 8, i1 = i0 + 4;
        int b00 = __builtin_amdgcn_ds_bpermute(i0, (int)rv.x);
        int b10 = __builtin_amdgcn_ds_bpermute(i0, (int)rv.y);
        int b20 = __builtin_amdgcn_ds_bpermute(i0, (int)rv.z);
        int b30 = __builtin_amdgcn_ds_bpermute(i0, (int)rv.w);
        int b01 = __builtin_amdgcn_ds_bpermute(i1, (int)rv.x);
        int b11 = __builtin_amdgcn_ds_bpermute(i1, (int)rv.y);
        int b21 = __builtin_amdgcn_ds_bpermute(i1, (int)rv.z);
        int b31 = __builtin_amdgcn_ds_bpermute(i1, (int)rv.w);
        d[0] = (u32)(h ? b10 : b00);
        d[1] = (u32)(h ? b11 : b01);
        d[2] = (u32)(h ? b30 : b20);
        d[3] = (u32)(h ? b31 : b21);
    };
    // dequant one octet (8 n) of a 64k strip-tile; zs unpacked per-element
    auto emit8 = [&](u32 w0, u32 w1, int nb, uint4 z0, uint4 z1) {
        char* bb = wbase + nb * 144;
        u32 w0s = w0 >> 4, w1s = w1 >> 4;
        auto em = [&](int j, u32 a0, u32 a1, int b, u32 zsj) {
            h2 mz = __builtin_bit_cast(h2, __builtin_amdgcn_perm(zsj, zsj, 0x01000100u));
            h2 s2 = __builtin_bit_cast(h2, __builtin_amdgcn_perm(zsj, zsj, 0x03020302u));
            u32 t = __builtin_amdgcn_perm(a1, a0, (u32)(b | ((b + 4) << 16)));
            u32 u = (t & 0x000F000Fu) | 0x64006400u;
            h2 v = (__builtin_bit_cast(h2, u) + mz) * s2;
            *(u32*)(bb + j * 144) = __builtin_bit_cast(u32, v);
        };
        em(0, w0, w1, 0, z0.x);  em(4, w0, w1, 1, z1.x);
        em(1, w0, w1, 2, z0.y);  em(5, w0, w1, 3, z1.y);
        em(2, w0s, w1s, 0, z0.z); em(6, w0s, w1s, 1, z1.z);
        em(3, w0s, w1s, 2, z0.w); em(7, w0s, w1s, 3, z1.w);
    };
    auto lda = [&](int k, uint4(&dst)[2][4]) {
        const int kb = k >> 5;
#pragma unroll
        for (int c = 0; c < 2; ++c)
#pragma unroll
            for (int mt = 0; mt < 4; ++mt)
                dst[c][mt] = *(const uint4*)(Ala + (size_t)((kb + c) * 8 + mh * 4 + mt) * 512);
    };

    uint4 rv_n = {0, 0, 0, 0};

    // ---- prologue: dequant B for first step ----
    loadzs(kc0 >> 7);
    uint4 rv0 = ldraw(kc0);
    if (kc0 + 64 < kend) rv_n = ldraw(kc0 + 64);
    {
        u32 qd[4];
        route(rv0, qd);
        emit8(qd[0], qd[1], h * 8, za0, za1);
        emit8(qd[2], qd[3], 16 + h * 8, zb0, zb1);
    }
    if (((kc0 + 64) & 127) == 0 && kc0 + 64 < kend)
        loadzs((kc0 + 64) >> 7);        // dn odd-sk mid-group start

    // ---- main loop ----
    for (int k0 = kc0; k0 < kend; k0 += 64) {
        const bool kn1 = (k0 + 64) < kend, kn2 = (k0 + 128) < kend;
        uint4 af[2][4];
        lda(k0, af);                                  // A(i), consumed by MFMA below
        // B-frags(i): region written during previous step (same-wave LDS order)
        uint4 bv[2][2];
#pragma unroll
        for (int c = 0; c < 2; ++c)
#pragma unroll
            for (int nt = 0; nt < 2; ++nt)
                bv[c][nt] = *(const uint4*)(myB + (nt * 16 + l16) * 144 + c * 64 + q * 16);
        uint4 rv_f = {0, 0, 0, 0};
        if (kn2) rv_f = ldraw(k0 + 128);              // raw(i+2)
        if (kn1) {                                    // dequant(i+1)
            u32 qd[4];
            route(rv_n, qd);
            emit8(qd[0], qd[1], h * 8, za0, za1);
            emit8(qd[2], qd[3], 16 + h * 8, zb0, zb1);
        }
        if (kn2 && (((k0 + 128) & 127) == 0))         // zs(group+1), used next step
            loadzs((k0 + 128) >> 7);
        // MFMA(i)
#pragma unroll
        for (int c = 0; c < 2; ++c)
#pragma unroll
            for (int mt = 0; mt < 4; ++mt)
#pragma unroll
                for (int nt = 0; nt < 2; ++nt)
                    acc[mt][nt] = __builtin_amdgcn_mfma_f32_16x16x32_f16(
                        __builtin_bit_cast(h8, af[c][mt]),
                        __builtin_bit_cast(h8, bv[c][nt]),
                        acc[mt][nt], 0, 0, 0);
        rv_n = rv_f;
    }

    // ---- epilogue: fp16 partial store ----
    u16* pp = part + (size_t)sk * M_TOK * N;
#pragma unroll
    for (int mt = 0; mt < 4; ++mt)
#pragma unroll
        for (int nt = 0; nt < 2; ++nt) {
            const int n = n0w + nt * 16 + l16;
#pragma unroll
            for (int r = 0; r < 4; ++r) {
                const int m = (mh * 4 + mt) * 16 + q * 4 + r;
                pp[(size_t)m * N + n] = f2h_(acc[mt][nt][r]);
            }
        }
}

// ---------------------------------------------------------------------------
__launch_bounds__(256)
__global__ void reduce_to_afrag(const u16* __restrict__ part, u16* __restrict__ out,
                                int SK) {
    const int idx = blockIdx.x * 256 + threadIdx.x;
    const int m = idx >> 9, c = idx & 511;
    float s[8] = {};
    for (int k = 0; k < SK; ++k)
        acc8(*(const uint4*)(part + (size_t)k * 524288 + (size_t)m * 4096 + c * 8), s);
    const int kb = c >> 2, qq = c & 3, mt = m >> 4, l16 = m & 15;
    u16 o8[8];
#pragma unroll
    for (int j = 0; j < 8; ++j) o8[j] = f2h_(s[j]);
    *(uint4*)(out + ((size_t)(kb * 8 + mt) * 64 + qq * 16 + l16) * 8) = *(const uint4*)o8;
}

__launch_bounds__(256)
__global__ void reduce_add_f32(const u16* __restrict__ part, const float* __restrict__ resin,
                               float* __restrict__ out, int SK) {
    const int idx = blockIdx.x * 256 + threadIdx.x;
    const size_t base = (size_t)idx * 8;
    float s[8];
    *(float4*)&s[0] = *(const float4*)(resin + base);
    *(float4*)&s[4] = *(const float4*)(resin + base + 4);
    for (int k = 0; k < SK; ++k)
        acc8(*(const uint4*)(part + (size_t)k * 524288 + base), s);
    *(float4*)(out + base)     = *(const float4*)&s[0];
    *(float4*)(out + base + 4) = *(const float4*)&s[4];
}

__launch_bounds__(256)
__global__ void silu_mul(const u16* __restrict__ part, u16* __restrict__ act) {
    const int idx = blockIdx.x * 256 + threadIdx.x;
    const int m = idx / 1376, c = idx - m * 1376;
    const int nb = c * 8;
    float g[8] = {}, u[8] = {};
    for (int k = 0; k < 3; ++k) {
        const size_t base = (size_t)k * 2818048 + (size_t)m * 22016 + nb;
        acc8(*(const uint4*)(part + base), g);
        acc8(*(const uint4*)(part + base + 11008), u);
    }
    const int kb = nb >> 5, qq = (nb >> 3) & 3, mt = m >> 4, l16 = m & 15;
    u16 o8[8];
#pragma unroll
    for (int j = 0; j < 8; ++j) {
        float a = g[j] / (1.f + __expf(-g[j])) * u[j];
        o8[j] = f2h_(a);
    }
    *(uint4*)(act + ((size_t)(kb * 8 + mt) * 64 + qq * 16 + l16) * 8) = *(const uint4*)o8;
}

// ---------------------------------------------------------------------------
extern "C" void kernel_launch(void* const* d_in, const int* in_sizes, int n_in,
                              void* d_out, int out_size, void* d_ws, size_t ws_size,
                              hipStream_t stream) {
    const float* x      = (const float*)d_in[0];
    const float* ln1_w  = (const float*)d_in[1];
    const float* ln2_w  = (const float*)d_in[2];
    const int*   qkv_qw = (const int*)d_in[3];
    const int*   qkv_qz = (const int*)d_in[4];
    const float* qkv_sc = (const float*)d_in[5];
    const int*   o_qw   = (const int*)d_in[6];
    const int*   o_qz   = (const int*)d_in[7];
    const float* o_sc   = (const float*)d_in[8];
    const int*   gu_qw  = (const int*)d_in[9];
    const int*   gu_qz  = (const int*)d_in[10];
    const float* gu_sc  = (const float*)d_in[11];
    const int*   dn_qw  = (const int*)d_in[12];
    const int*   dn_qz  = (const int*)d_in[13];
    const float* dn_sc  = (const float*)d_in[14];
    float* out = (float*)d_out;

    // ws layout (~25.7 MB)
    char* ws = (char*)d_ws;
    u16*   pbuf = (u16*)(ws);                 // partials: max 16.9 MB (gu SK3)
    u32*   zsb  = (u32*)(ws + 16908288);      // 2.82 MB, reused per gemm
    u16*   act  = (u16*)(ws + 19726336);      // 2.75 MB fp16 (Afrag)
    float* res2 = (float*)(ws + 22544384);    // 2 MB fp32
    u16*   slot = (u16*)(ws + 24641536);      // 1 MB fp16 Afrag (h1/qb/h2)

    // h1 = rmsnorm(x, ln1) -> Afrag ; zs for qkv
    rmsnorm_k<<<128, 256, 0, stream>>>(x, ln1_w, slot);
    pack_zs<<<512, 256, 0, stream>>>(qkv_qz, qkv_sc, zsb, 1536, 12288, 4096, 131072);

    // q = h1 @ Wqkv[:, :4096]   (64 tiles x SK16, kchunk 256)
    gemm_awq<<<dim3(64, 16), 256, 0, stream>>>(slot, zsb, qkv_qw, pbuf,
                                               1536, 4096, 4096, 256);
    reduce_to_afrag<<<256, 256, 0, stream>>>(pbuf, slot, 16);
    pack_zs<<<512, 256, 0, stream>>>(o_qz, o_sc, zsb, 512, 4096, 4096, 131072);

    // attn = q @ Wo ; res2 = x + attn
    gemm_awq<<<dim3(64, 16), 256, 0, stream>>>(slot, zsb, o_qw, pbuf,
                                               512, 4096, 4096, 256);
    reduce_add_f32<<<256, 256, 0, stream>>>(pbuf, x, res2, 16);

    // h2 = rmsnorm(res2, ln2) -> Afrag ; zs for gu
    rmsnorm_k<<<128, 256, 0, stream>>>(res2, ln2_w, slot);
    pack_zs<<<2752, 256, 0, stream>>>(gu_qz, gu_sc, zsb, 2752, 22016, 22016, 704512);

    // gate_up = h2 @ Wgu   (344 tiles x SK3, kchunk 1408)
    gemm_awq<<<dim3(344, 3), 256, 0, stream>>>(slot, zsb, gu_qw, pbuf,
                                               2752, 22016, 4096, 1408);
    silu_mul<<<688, 256, 0, stream>>>(pbuf, act);
    pack_zs<<<1376, 256, 0, stream>>>(dn_qz, dn_sc, zsb, 512, 4096, 4096, 352256);

    // down = act @ Wdn   (64 tiles x SK16, kchunk 704); out = res2 + down
    gemm_awq<<<dim3(64, 16), 256, 0, stream>>>(act, zsb, dn_qw, pbuf,
                                               512, 4096, 11008, 704);
    reduce_add_f32<<<256, 256, 0, stream>>>(pbuf, res2, out, 16);
}

// Round 3
// 339.151 us; speedup vs baseline: 1.0014x; 1.0014x over previous
//
#include <hip/hip_runtime.h>

typedef unsigned int   u32;
typedef unsigned short u16;

typedef _Float16 h2  __attribute__((ext_vector_type(2)));
typedef _Float16 h8  __attribute__((ext_vector_type(8)));
typedef float    f32x4 __attribute__((ext_vector_type(4)));

#define M_TOK 128

__device__ __forceinline__ u16 f2h_(float f) {
    _Float16 h = (_Float16)f; return __builtin_bit_cast(u16, h);
}
__device__ __forceinline__ float h2f_(u16 b) {
    _Float16 h = __builtin_bit_cast(_Float16, b); return (float)h;
}
__device__ __forceinline__ void acc8(uint4 v, float* s) {
#pragma unroll
    for (int i = 0; i < 4; ++i) {
        u32 w = ((const u32*)&v)[i];
        s[2 * i]     += h2f_((u16)(w & 0xFFFF));
        s[2 * i + 1] += h2f_((u16)(w >> 16));
    }
}

// AWQ nibble order: n&7 = j sits at bit position SH[j]
__constant__ int SHC[8] = {0, 16, 4, 20, 8, 24, 12, 28};

// ---------------------------------------------------------------------------
// pack_zs: (qz, sc) -> zs[g][n] u32 { lo16: fp16(-(1024+z)), hi16: fp16(sc) }
// ---------------------------------------------------------------------------
__launch_bounds__(256)
__global__ void pack_zs(const int* __restrict__ qz, const float* __restrict__ sc,
                        u32* __restrict__ zs, int qws, int scs, int Ncols, int total) {
    const int idx = blockIdx.x * 256 + threadIdx.x;
    if (idx >= total) return;
    const int g = idx / Ncols, n = idx - g * Ncols;
    const u32 d = (u32)qz[(size_t)g * qws + (n >> 3)];
    const u32 zj = (d >> SHC[n & 7]) & 15u;
    const u32 mz = 0xE400u | zj;                    // fp16 -(1024+z)
    const u16 sh = f2h_(sc[(size_t)g * scs + n]);
    zs[(size_t)g * Ncols + n] = mz | ((u32)sh << 16);
}

// ---------------------------------------------------------------------------
// repack_qw: transpose k-major qw into per-(granule g = 32n, step s = 64k, lane)
// uint4 streams matching gemm consumption exactly (route permutation baked in).
// Lane (kp=lane&31, h=lane>>5) at (g, s) gets:
//   { qw[64s+2kp][4g+h], qw[64s+2kp+1][4g+h],
//     qw[64s+2kp][4g+h+2], qw[64s+2kp+1][4g+h+2] }
// Block = 4 granules x 64 lanes: reads 64 rows x 64 B -> every touched line
// fully consumed (via L1/L2). Writes: 4 x 1 KB contiguous runs.
// ---------------------------------------------------------------------------
__launch_bounds__(256)
__global__ void repack_qw(const int* __restrict__ qw, uint4* __restrict__ qout,
                          int qws, int ST /* = K/64 */) {
    const int t = threadIdx.x;
    const int j = t >> 6, lane = t & 63;
    const int kp = lane & 31, h = lane >> 5;
    const int g = blockIdx.x * 4 + j;
    const int s = blockIdx.y;
    const int r0 = s * 64 + kp * 2;
    const int* base = qw + (size_t)r0 * qws + 4 * g + h;
    uint4 o;
    o.x = (u32)base[0];
    o.y = (u32)base[qws];
    o.z = (u32)base[2];
    o.w = (u32)base[qws + 2];
    qout[((size_t)g * ST + s) * 64 + lane] = o;
}

// A-fragment-major layout: elem offset for logical (m, k):
//   kb=k/32, q=(k/8)&3, j=k&7, mt=m/16, l16=m&15
//   off = ((kb*8+mt)*64 + q*16 + l16)*8 + j    (fp16 elements)

// ---------------------------------------------------------------------------
// RMSNorm: one block per token row, fp32 in -> fp16 out in Afrag layout
// ---------------------------------------------------------------------------
__launch_bounds__(256)
__global__ void rmsnorm_k(const float* __restrict__ in, const float* __restrict__ w,
                          u16* __restrict__ out) {
    const int row = blockIdx.x;
    const float* x = in + (size_t)row * 4096;
    float ss = 0.f;
#pragma unroll
    for (int j = 0; j < 16; ++j) {
        float v = x[threadIdx.x + 256 * j];
        ss += v * v;
    }
#pragma unroll
    for (int off = 32; off > 0; off >>= 1) ss += __shfl_down(ss, off, 64);
    __shared__ float ws4[4];
    if ((threadIdx.x & 63) == 0) ws4[threadIdx.x >> 6] = ss;
    __syncthreads();
    float total = ws4[0] + ws4[1] + ws4[2] + ws4[3];
    float r = rsqrtf(total * (1.f / 4096.f) + 1e-6f);
    const int mt = row >> 4, l16 = row & 15;
#pragma unroll
    for (int c2 = 0; c2 < 2; ++c2) {
        int c = threadIdx.x * 2 + c2;
        int kb = c >> 2, qq = c & 3;
        u16 o8[8];
#pragma unroll
        for (int j = 0; j < 8; ++j) {
            int i = c * 8 + j;
            o8[j] = f2h_(x[i] * r * w[i]);
        }
        *(uint4*)(out + ((size_t)(kb * 8 + mt) * 64 + qq * 16 + l16) * 8) = *(const uint4*)o8;
    }
}

// ---------------------------------------------------------------------------
// AWQ GEMM, barrier-free, A depth-2 register double-buffer (round-0 structure).
// Per wave: 128m x 32n strip, BK=64/iter, private LDS B (in-order, no barrier).
// RP=1: qw repacked -> each ldraw is a contiguous 1 KB wave load, route deleted.
// RP=0: original per-lane row gather + ds_bpermute route (ws fallback).
// ---------------------------------------------------------------------------
template<int RP>
__launch_bounds__(256, 2)
__global__ void gemm_awq(const u16* __restrict__ A, const u32* __restrict__ zs,
                         const void* __restrict__ qwv, u16* __restrict__ part,
                         int qws, int N, int K, int kchunk) {
    __shared__ __align__(16) char ldsB[4 * 4608];   // per-wave 32 rows x 144 B

    const int tid = threadIdx.x, w = tid >> 6, lane = tid & 63;
    const int q = lane >> 4, l16 = lane & 15;
    const int n0w = blockIdx.x * 128 + w * 32;
    const int pc0 = n0w >> 3;
    const int kp = lane & 31, h = lane >> 5;
    const int sk = blockIdx.y, kc0 = sk * kchunk, kend = min(kc0 + kchunk, K);

    char* myB   = ldsB + w * 4608;
    char* wbase = myB + kp * 4;
    const u16* Ala = A + lane * 8;
    const int* qws_base = (const int*)qwv + pc0;
    const uint4* qrp = (const uint4*)qwv + (size_t)(n0w >> 5) * (K >> 6) * 64 + lane;
    const u32* zsA = zs + n0w + h * 8;
    const u32* zsB = zs + n0w + 16 + h * 8;

    f32x4 acc[8][2] = {};
    uint4 za0, za1, zb0, zb1;       // current group's packed (mz, sc)

    auto ldraw = [&](int k0) -> uint4 {
        if (RP) return qrp[(size_t)(k0 >> 6) * 64];
        return *(const uint4*)(qws_base + (size_t)(k0 + lane) * qws);
    };
    auto loadzs = [&](int g) {
        za0 = *(const uint4*)(zsA + (size_t)g * N);
        za1 = *(const uint4*)(zsA + (size_t)g * N + 4);
        zb0 = *(const uint4*)(zsB + (size_t)g * N);
        zb1 = *(const uint4*)(zsB + (size_t)g * N + 4);
    };
    auto route = [&](uint4 rv, u32* d) {
        const int i0 = kp * 8, i1 = i0 + 4;
        int b00 = __builtin_amdgcn_ds_bpermute(i0, (int)rv.x);
        int b10 = __builtin_amdgcn_ds_bpermute(i0, (int)rv.y);
        int b20 = __builtin_amdgcn_ds_bpermute(i0, (int)rv.z);
        int b30 = __builtin_amdgcn_ds_bpermute(i0, (int)rv.w);
        int b01 = __builtin_amdgcn_ds_bpermute(i1, (int)rv.x);
        int b11 = __builtin_amdgcn_ds_bpermute(i1, (int)rv.y);
        int b21 = __builtin_amdgcn_ds_bpermute(i1, (int)rv.z);
        int b31 = __builtin_amdgcn_ds_bpermute(i1, (int)rv.w);
        d[0] = (u32)(h ? b10 : b00);
        d[1] = (u32)(h ? b11 : b01);
        d[2] = (u32)(h ? b30 : b20);
        d[3] = (u32)(h ? b31 : b21);
    };
    // dequant one octet (8 n) of a 64k strip-tile; zs unpacked per-element
    auto emit8 = [&](u32 w0, u32 w1, int nb, uint4 z0, uint4 z1) {
        char* bb = wbase + nb * 144;
        u32 w0s = w0 >> 4, w1s = w1 >> 4;
        auto em = [&](int j, u32 a0, u32 a1, int b, u32 zsj) {
            h2 mz = __builtin_bit_cast(h2, __builtin_amdgcn_perm(zsj, zsj, 0x01000100u));
            h2 s2 = __builtin_bit_cast(h2, __builtin_amdgcn_perm(zsj, zsj, 0x03020302u));
            u32 t = __builtin_amdgcn_perm(a1, a0, (u32)(b | ((b + 4) << 16)));
            u32 u = (t & 0x000F000Fu) | 0x64006400u;
            h2 v = (__builtin_bit_cast(h2, u) + mz) * s2;
            *(u32*)(bb + j * 144) = __builtin_bit_cast(u32, v);
        };
        em(0, w0, w1, 0, z0.x);  em(4, w0, w1, 1, z1.x);
        em(1, w0, w1, 2, z0.y);  em(5, w0, w1, 3, z1.y);
        em(2, w0s, w1s, 0, z0.z); em(6, w0s, w1s, 1, z1.z);
        em(3, w0s, w1s, 2, z0.w); em(7, w0s, w1s, 3, z1.w);
    };
    auto dq = [&](uint4 rv) {
        u32 qd[4];
        if (RP) { qd[0] = rv.x; qd[1] = rv.y; qd[2] = rv.z; qd[3] = rv.w; }
        else route(rv, qd);
        emit8(qd[0], qd[1], h * 8, za0, za1);
        emit8(qd[2], qd[3], 16 + h * 8, zb0, zb1);
    };
    auto lda = [&](int k, uint4(&dst)[2][8]) {
        const int kb = k >> 5;
#pragma unroll
        for (int c = 0; c < 2; ++c)
#pragma unroll
            for (int mt = 0; mt < 8; ++mt)
                dst[c][mt] = *(const uint4*)(Ala + (size_t)((kb + c) * 8 + mt) * 512);
    };

    uint4 afA[2][8], afB[2][8];
    uint4 rv_n = {0, 0, 0, 0};

    // ---- prologue ----
    loadzs(kc0 >> 7);
    uint4 rv0 = ldraw(kc0);
    if (kc0 + 64 < kend) rv_n = ldraw(kc0 + 64);
    lda(kc0, afA);
    dq(rv0);
    if (((kc0 + 64) & 127) == 0 && kc0 + 64 < kend)
        loadzs((kc0 + 64) >> 7);        // dn odd-sk mid-group start

    // ---- main loop: unrolled ping-pong pair ----
    auto step = [&](int k0, uint4(&cur)[2][8], uint4(&nxt)[2][8]) {
        const bool kn1 = (k0 + 64) < kend, kn2 = (k0 + 128) < kend;
        if (kn1) lda(k0 + 64, nxt);                   // A(i+1), consumed next step
        // B-frags(i): region written during previous step (same-wave order)
        uint4 bv[2][2];
#pragma unroll
        for (int c = 0; c < 2; ++c)
#pragma unroll
            for (int nt = 0; nt < 2; ++nt)
                bv[c][nt] = *(const uint4*)(myB + (nt * 16 + l16) * 144 + c * 64 + q * 16);
        uint4 rv_f = {0, 0, 0, 0};
        if (kn2) rv_f = ldraw(k0 + 128);              // raw(i+2)
        if (kn1) dq(rv_n);                            // dequant(i+1)
        if (kn2 && (((k0 + 128) & 127) == 0))         // zs(group+1), used next step
            loadzs((k0 + 128) >> 7);
        // MFMA(i): all operands from previous step
#pragma unroll
        for (int c = 0; c < 2; ++c)
#pragma unroll
            for (int mt = 0; mt < 8; ++mt)
#pragma unroll
                for (int nt = 0; nt < 2; ++nt)
                    acc[mt][nt] = __builtin_amdgcn_mfma_f32_16x16x32_f16(
                        __builtin_bit_cast(h8, cur[c][mt]),
                        __builtin_bit_cast(h8, bv[c][nt]),
                        acc[mt][nt], 0, 0, 0);
        rv_n = rv_f;
    };
    for (int k0 = kc0; k0 < kend; k0 += 128) {
        step(k0, afA, afB);
        if (k0 + 64 < kend) step(k0 + 64, afB, afA);
    }

    // ---- epilogue: fp16 partial store ----
    u16* pp = part + (size_t)sk * M_TOK * N;
#pragma unroll
    for (int mt = 0; mt < 8; ++mt)
#pragma unroll
        for (int nt = 0; nt < 2; ++nt) {
            const int n = n0w + nt * 16 + l16;
#pragma unroll
            for (int r = 0; r < 4; ++r) {
                const int m = mt * 16 + q * 4 + r;
                pp[(size_t)m * N + n] = f2h_(acc[mt][nt][r]);
            }
        }
}

// ---------------------------------------------------------------------------
__launch_bounds__(256)
__global__ void reduce_to_afrag(const u16* __restrict__ part, u16* __restrict__ out,
                                int SK) {
    const int idx = blockIdx.x * 256 + threadIdx.x;
    const int m = idx >> 9, c = idx & 511;
    float s[8] = {};
    for (int k = 0; k < SK; ++k)
        acc8(*(const uint4*)(part + (size_t)k * 524288 + (size_t)m * 4096 + c * 8), s);
    const int kb = c >> 2, qq = c & 3, mt = m >> 4, l16 = m & 15;
    u16 o8[8];
#pragma unroll
    for (int j = 0; j < 8; ++j) o8[j] = f2h_(s[j]);
    *(uint4*)(out + ((size_t)(kb * 8 + mt) * 64 + qq * 16 + l16) * 8) = *(const uint4*)o8;
}

__launch_bounds__(256)
__global__ void reduce_add_f32(const u16* __restrict__ part, const float* __restrict__ resin,
                               float* __restrict__ out, int SK) {
    const int idx = blockIdx.x * 256 + threadIdx.x;
    const size_t base = (size_t)idx * 8;
    float s[8];
    *(float4*)&s[0] = *(const float4*)(resin + base);
    *(float4*)&s[4] = *(const float4*)(resin + base + 4);
    for (int k = 0; k < SK; ++k)
        acc8(*(const uint4*)(part + (size_t)k * 524288 + base), s);
    *(float4*)(out + base)     = *(const float4*)&s[0];
    *(float4*)(out + base + 4) = *(const float4*)&s[4];
}

__launch_bounds__(256)
__global__ void silu_mul(const u16* __restrict__ part, u16* __restrict__ act) {
    const int idx = blockIdx.x * 256 + threadIdx.x;
    const int m = idx / 1376, c = idx - m * 1376;
    const int nb = c * 8;
    float g[8] = {}, u[8] = {};
    for (int k = 0; k < 3; ++k) {
        const size_t base = (size_t)k * 2818048 + (size_t)m * 22016 + nb;
        acc8(*(const uint4*)(part + base), g);
        acc8(*(const uint4*)(part + base + 11008), u);
    }
    const int kb = nb >> 5, qq = (nb >> 3) & 3, mt = m >> 4, l16 = m & 15;
    u16 o8[8];
#pragma unroll
    for (int j = 0; j < 8; ++j) {
        float a = g[j] / (1.f + __expf(-g[j])) * u[j];
        o8[j] = f2h_(a);
    }
    *(uint4*)(act + ((size_t)(kb * 8 + mt) * 64 + qq * 16 + l16) * 8) = *(const uint4*)o8;
}

// ---------------------------------------------------------------------------
extern "C" void kernel_launch(void* const* d_in, const int* in_sizes, int n_in,
                              void* d_out, int out_size, void* d_ws, size_t ws_size,
                              hipStream_t stream) {
    const float* x      = (const float*)d_in[0];
    const float* ln1_w  = (const float*)d_in[1];
    const float* ln2_w  = (const float*)d_in[2];
    const int*   qkv_qw = (const int*)d_in[3];
    const int*   qkv_qz = (const int*)d_in[4];
    const float* qkv_sc = (const float*)d_in[5];
    const int*   o_qw   = (const int*)d_in[6];
    const int*   o_qz   = (const int*)d_in[7];
    const float* o_sc   = (const float*)d_in[8];
    const int*   gu_qw  = (const int*)d_in[9];
    const int*   gu_qz  = (const int*)d_in[10];
    const float* gu_sc  = (const float*)d_in[11];
    const int*   dn_qw  = (const int*)d_in[12];
    const int*   dn_qz  = (const int*)d_in[13];
    const float* dn_sc  = (const float*)d_in[14];
    float* out = (float*)d_out;

    // ws layout
    char* ws = (char*)d_ws;
    u16*   pbuf = (u16*)(ws);                 // partials: max 16.9 MB (gu SK3)
    u32*   zsb  = (u32*)(ws + 16908288);      // 2.82 MB, reused per gemm
    u16*   act  = (u16*)(ws + 19726336);      // 2.75 MB fp16 (Afrag)
    float* res2 = (float*)(ws + 22544384);    // 2 MB fp32
    u16*   slot = (u16*)(ws + 24641536);      // 1 MB fp16 Afrag (h1/qb/h2)
    uint4* qwr  = (uint4*)(ws + 25690112);    // repacked qw, max 45.1 MB (gu)
    // Tiered gating on available workspace:
    //   full: repack all four weights (gu needs 45.09 MB -> end 70778880)
    //   mid:  repack qkv/o/dn only (dn needs 22.54 MB -> end 48234496)
    const bool rp_full = ws_size >= 70778880u;
    const bool rp_mid  = ws_size >= 48234496u;

    // h1 = rmsnorm(x, ln1) -> Afrag ; zs for qkv
    rmsnorm_k<<<128, 256, 0, stream>>>(x, ln1_w, slot);
    pack_zs<<<512, 256, 0, stream>>>(qkv_qz, qkv_sc, zsb, 1536, 12288, 4096, 131072);

    // q = h1 @ Wqkv[:, :4096]   (32 tiles x SK16, kchunk 256)
    if (rp_mid) {
        repack_qw<<<dim3(32, 64), 256, 0, stream>>>(qkv_qw, qwr, 1536, 64);
        gemm_awq<1><<<dim3(32, 16), 256, 0, stream>>>(slot, zsb, qwr, pbuf,
                                                      1536, 4096, 4096, 256);
    } else {
        gemm_awq<0><<<dim3(32, 16), 256, 0, stream>>>(slot, zsb, qkv_qw, pbuf,
                                                      1536, 4096, 4096, 256);
    }
    reduce_to_afrag<<<256, 256, 0, stream>>>(pbuf, slot, 16);
    pack_zs<<<512, 256, 0, stream>>>(o_qz, o_sc, zsb, 512, 4096, 4096, 131072);

    // attn = q @ Wo ; res2 = x + attn
    if (rp_mid) {
        repack_qw<<<dim3(32, 64), 256, 0, stream>>>(o_qw, qwr, 512, 64);
        gemm_awq<1><<<dim3(32, 16), 256, 0, stream>>>(slot, zsb, qwr, pbuf,
                                                      512, 4096, 4096, 256);
    } else {
        gemm_awq<0><<<dim3(32, 16), 256, 0, stream>>>(slot, zsb, o_qw, pbuf,
                                                      512, 4096, 4096, 256);
    }
    reduce_add_f32<<<256, 256, 0, stream>>>(pbuf, x, res2, 16);

    // h2 = rmsnorm(res2, ln2) -> Afrag ; zs for gu
    rmsnorm_k<<<128, 256, 0, stream>>>(res2, ln2_w, slot);
    pack_zs<<<2752, 256, 0, stream>>>(gu_qz, gu_sc, zsb, 2752, 22016, 22016, 704512);

    // gate_up = h2 @ Wgu   (172 tiles x SK3, kchunk 1408)
    if (rp_full) {
        repack_qw<<<dim3(172, 64), 256, 0, stream>>>(gu_qw, qwr, 2752, 64);
        gemm_awq<1><<<dim3(172, 3), 256, 0, stream>>>(slot, zsb, qwr, pbuf,
                                                      2752, 22016, 4096, 1408);
    } else {
        gemm_awq<0><<<dim3(172, 3), 256, 0, stream>>>(slot, zsb, gu_qw, pbuf,
                                                      2752, 22016, 4096, 1408);
    }
    silu_mul<<<688, 256, 0, stream>>>(pbuf, act);
    pack_zs<<<1376, 256, 0, stream>>>(dn_qz, dn_sc, zsb, 512, 4096, 4096, 352256);

    // down = act @ Wdn   (32 tiles x SK16, kchunk 704); out = res2 + down
    if (rp_mid) {
        repack_qw<<<dim3(32, 172), 256, 0, stream>>>(dn_qw, qwr, 512, 172);
        gemm_awq<1><<<dim3(32, 16), 256, 0, stream>>>(act, zsb, qwr, pbuf,
                                                      512, 4096, 11008, 704);
    } else {
        gemm_awq<0><<<dim3(32, 16), 256, 0, stream>>>(act, zsb, dn_qw, pbuf,
                                                      512, 4096, 11008, 704);
    }
    reduce_add_f32<<<256, 256, 0, stream>>>(pbuf, res2, out, 16);
}

// Round 4
// 307.156 us; speedup vs baseline: 1.1057x; 1.1042x over previous
//
#include <hip/hip_runtime.h>

typedef unsigned int   u32;
typedef unsigned short u16;

typedef _Float16 h2  __attribute__((ext_vector_type(2)));
typedef _Float16 h8  __attribute__((ext_vector_type(8)));
typedef float    f32x4 __attribute__((ext_vector_type(4)));

#define M_TOK 128

__device__ __forceinline__ u16 f2h_(float f) {
    _Float16 h = (_Float16)f; return __builtin_bit_cast(u16, h);
}
__device__ __forceinline__ float h2f_(u16 b) {
    _Float16 h = __builtin_bit_cast(_Float16, b); return (float)h;
}
__device__ __forceinline__ void acc8(uint4 v, float* s) {
#pragma unroll
    for (int i = 0; i < 4; ++i) {
        u32 w = ((const u32*)&v)[i];
        s[2 * i]     += h2f_((u16)(w & 0xFFFF));
        s[2 * i + 1] += h2f_((u16)(w >> 16));
    }
}

// AWQ nibble order: n&7 = j sits at bit position SH[j]
__constant__ int SHC[8] = {0, 16, 4, 20, 8, 24, 12, 28};

// ---------------------------------------------------------------------------
// pack_zs: (qz, sc) -> zs[g][n] u32 { lo16: fp16(-(1024+z)), hi16: fp16(sc) }
// ---------------------------------------------------------------------------
__launch_bounds__(256)
__global__ void pack_zs(const int* __restrict__ qz, const float* __restrict__ sc,
                        u32* __restrict__ zs, int qws, int scs, int Ncols, int total) {
    const int idx = blockIdx.x * 256 + threadIdx.x;
    if (idx >= total) return;
    const int g = idx / Ncols, n = idx - g * Ncols;
    const u32 d = (u32)qz[(size_t)g * qws + (n >> 3)];
    const u32 zj = (d >> SHC[n & 7]) & 15u;
    const u32 mz = 0xE400u | zj;                    // fp16 -(1024+z)
    const u16 sh = f2h_(sc[(size_t)g * scs + n]);
    zs[(size_t)g * Ncols + n] = mz | ((u32)sh << 16);
}

// A-fragment-major layout: elem offset for logical (m, k):
//   kb=k/32, q=(k/8)&3, j=k&7, mt=m/16, l16=m&15
//   off = ((kb*8+mt)*64 + q*16 + l16)*8 + j    (fp16 elements)

// ---------------------------------------------------------------------------
// RMSNorm: one block per token row, fp32 in -> fp16 out in Afrag layout
// ---------------------------------------------------------------------------
__launch_bounds__(256)
__global__ void rmsnorm_k(const float* __restrict__ in, const float* __restrict__ w,
                          u16* __restrict__ out) {
    const int row = blockIdx.x;
    const float* x = in + (size_t)row * 4096;
    float ss = 0.f;
#pragma unroll
    for (int j = 0; j < 16; ++j) {
        float v = x[threadIdx.x + 256 * j];
        ss += v * v;
    }
#pragma unroll
    for (int off = 32; off > 0; off >>= 1) ss += __shfl_down(ss, off, 64);
    __shared__ float ws4[4];
    if ((threadIdx.x & 63) == 0) ws4[threadIdx.x >> 6] = ss;
    __syncthreads();
    float total = ws4[0] + ws4[1] + ws4[2] + ws4[3];
    float r = rsqrtf(total * (1.f / 4096.f) + 1e-6f);
    const int mt = row >> 4, l16 = row & 15;
#pragma unroll
    for (int c2 = 0; c2 < 2; ++c2) {
        int c = threadIdx.x * 2 + c2;
        int kb = c >> 2, qq = c & 3;
        u16 o8[8];
#pragma unroll
        for (int j = 0; j < 8; ++j) {
            int i = c * 8 + j;
            o8[j] = f2h_(x[i] * r * w[i]);
        }
        *(uint4*)(out + ((size_t)(kb * 8 + mt) * 64 + qq * 16 + l16) * 8) = *(const uint4*)o8;
    }
}

// ---------------------------------------------------------------------------
// AWQ GEMM. Wave tile 64m x 32n; block 128m x 64n (2 m-halves x 2 n-halves).
// Per-wave private LDS B region, same-wave write(i+1)/read(i) in-order.
// The mh-pair waves of each n-half duplicate ldraw/route/dequant; a per-step
// __syncthreads() bounds their drift to <=1 step so the duplicate qw reads
// hit L1/L2 on the same CU (round-1 without the barrier doubled HBM FETCH).
// __launch_bounds__(256,4): ~84 unified regs -> 4 waves/SIMD; grids sized
// ~4-5 blocks/CU. Chunked XCD swizzle on blockIdx.x: adjacent n-tiles (same
// weight rows/DRAM pages) land on the same XCD L2.
// ---------------------------------------------------------------------------
__launch_bounds__(256, 4)
__global__ void gemm_awq(const u16* __restrict__ A, const u32* __restrict__ zs,
                         const int* __restrict__ qw, u16* __restrict__ part,
                         int qws, int N, int K, int kchunk) {
    __shared__ __align__(16) char ldsB[4 * 4608];   // per-wave 32 rows x 144 B

    const int tid = threadIdx.x, w = tid >> 6, lane = tid & 63;
    const int q = lane >> 4, l16 = lane & 15;
    const int mh = w >> 1;                           // m-half: rows [mh*64, mh*64+64)
    // chunked XCD swizzle (gridDim.x is a multiple of 8 for all call sites)
    const int bx = (blockIdx.x & 7) * (gridDim.x >> 3) + (blockIdx.x >> 3);
    const int n0w = bx * 64 + (w & 1) * 32;          // 32n strip of this wave
    const int pc0 = n0w >> 3;
    const int kp = lane & 31, h = lane >> 5;
    const int sk = blockIdx.y, kc0 = sk * kchunk, kend = min(kc0 + kchunk, K);

    char* myB   = ldsB + w * 4608;
    char* wbase = myB + kp * 4;
    const u16* Ala = A + lane * 8;
    const int* qws_base = qw + pc0;
    const u32* zsA = zs + n0w + h * 8;
    const u32* zsB = zs + n0w + 16 + h * 8;

    f32x4 acc[4][2] = {};
    uint4 za0, za1, zb0, zb1;       // current group's packed (mz, sc)

    auto ldraw = [&](int k0) -> uint4 {
        return *(const uint4*)(qws_base + (size_t)(k0 + lane) * qws);
    };
    auto loadzs = [&](int g) {
        za0 = *(const uint4*)(zsA + (size_t)g * N);
        za1 = *(const uint4*)(zsA + (size_t)g * N + 4);
        zb0 = *(const uint4*)(zsB + (size_t)g * N);
        zb1 = *(const uint4*)(zsB + (size_t)g * N + 4);
    };
    auto route = [&](uint4 rv, u32* d) {
        const int i0 = kp * 8, i1 = i0 + 4;
        int b00 = __builtin_amdgcn_ds_bpermute(i0, (int)rv.x);
        int b10 = __builtin_amdgcn_ds_bpermute(i0, (int)rv.y);
        int b20 = __builtin_amdgcn_ds_bpermute(i0, (int)rv.z);
        int b30 = __builtin_amdgcn_ds_bpermute(i0, (int)rv.w);
        int b01 = __builtin_amdgcn_ds_bpermute(i1, (int)rv.x);
        int b11 = __builtin_amdgcn_ds_bpermute(i1, (int)rv.y);
        int b21 = __builtin_amdgcn_ds_bpermute(i1, (int)rv.z);
        int b31 = __builtin_amdgcn_ds_bpermute(i1, (int)rv.w);
        d[0] = (u32)(h ? b10 : b00);
        d[1] = (u32)(h ? b11 : b01);
        d[2] = (u32)(h ? b30 : b20);
        d[3] = (u32)(h ? b31 : b21);
    };
    // dequant one octet (8 n) of a 64k strip-tile; zs unpacked per-element
    auto emit8 = [&](u32 w0, u32 w1, int nb, uint4 z0, uint4 z1) {
        char* bb = wbase + nb * 144;
        u32 w0s = w0 >> 4, w1s = w1 >> 4;
        auto em = [&](int j, u32 a0, u32 a1, int b, u32 zsj) {
            h2 mz = __builtin_bit_cast(h2, __builtin_amdgcn_perm(zsj, zsj, 0x01000100u));
            h2 s2 = __builtin_bit_cast(h2, __builtin_amdgcn_perm(zsj, zsj, 0x03020302u));
            u32 t = __builtin_amdgcn_perm(a1, a0, (u32)(b | ((b + 4) << 16)));
            u32 u = (t & 0x000F000Fu) | 0x64006400u;
            h2 v = (__builtin_bit_cast(h2, u) + mz) * s2;
            *(u32*)(bb + j * 144) = __builtin_bit_cast(u32, v);
        };
        em(0, w0, w1, 0, z0.x);  em(4, w0, w1, 1, z1.x);
        em(1, w0, w1, 2, z0.y);  em(5, w0, w1, 3, z1.y);
        em(2, w0s, w1s, 0, z0.z); em(6, w0s, w1s, 1, z1.z);
        em(3, w0s, w1s, 2, z0.w); em(7, w0s, w1s, 3, z1.w);
    };
    auto dq = [&](uint4 rv) {
        u32 qd[4];
        route(rv, qd);
        emit8(qd[0], qd[1], h * 8, za0, za1);
        emit8(qd[2], qd[3], 16 + h * 8, zb0, zb1);
    };
    auto lda = [&](int k, uint4(&dst)[2][4]) {
        const int kb = k >> 5;
#pragma unroll
        for (int c = 0; c < 2; ++c)
#pragma unroll
            for (int mt = 0; mt < 4; ++mt)
                dst[c][mt] = *(const uint4*)(Ala + (size_t)((kb + c) * 8 + mh * 4 + mt) * 512);
    };

    uint4 rv_n = {0, 0, 0, 0};

    // ---- prologue: dequant B for first step ----
    loadzs(kc0 >> 7);
    uint4 rv0 = ldraw(kc0);
    if (kc0 + 64 < kend) rv_n = ldraw(kc0 + 64);
    {
        u32 qd[4];
        route(rv0, qd);
        emit8(qd[0], qd[1], h * 8, za0, za1);
        emit8(qd[2], qd[3], 16 + h * 8, zb0, zb1);
    }
    if (((kc0 + 64) & 127) == 0 && kc0 + 64 < kend)
        loadzs((kc0 + 64) >> 7);        // mid-group chunk start (dn)

    // ---- main loop ----
    for (int k0 = kc0; k0 < kend; k0 += 64) {
        __syncthreads();    // timing-only: keep mh-pairs aligned for L1/L2 reuse
        const bool kn1 = (k0 + 64) < kend, kn2 = (k0 + 128) < kend;
        uint4 af[2][4];
        lda(k0, af);                                  // A(i), consumed by MFMA below
        // B-frags(i): region written during previous step (same-wave LDS order)
        uint4 bv[2][2];
#pragma unroll
        for (int c = 0; c < 2; ++c)
#pragma unroll
            for (int nt = 0; nt < 2; ++nt)
                bv[c][nt] = *(const uint4*)(myB + (nt * 16 + l16) * 144 + c * 64 + q * 16);
        uint4 rv_f = {0, 0, 0, 0};
        if (kn2) rv_f = ldraw(k0 + 128);              // raw(i+2)
        if (kn1) {                                    // dequant(i+1)
            u32 qd[4];
            route(rv_n, qd);
            emit8(qd[0], qd[1], h * 8, za0, za1);
            emit8(qd[2], qd[3], 16 + h * 8, zb0, zb1);
        }
        if (kn2 && (((k0 + 128) & 127) == 0))         // zs(group+1), used next step
            loadzs((k0 + 128) >> 7);
        // MFMA(i)
#pragma unroll
        for (int c = 0; c < 2; ++c)
#pragma unroll
            for (int mt = 0; mt < 4; ++mt)
#pragma unroll
                for (int nt = 0; nt < 2; ++nt)
                    acc[mt][nt] = __builtin_amdgcn_mfma_f32_16x16x32_f16(
                        __builtin_bit_cast(h8, af[c][mt]),
                        __builtin_bit_cast(h8, bv[c][nt]),
                        acc[mt][nt], 0, 0, 0);
        rv_n = rv_f;
    }

    // ---- epilogue: fp16 partial store ----
    u16* pp = part + (size_t)sk * M_TOK * N;
#pragma unroll
    for (int mt = 0; mt < 4; ++mt)
#pragma unroll
        for (int nt = 0; nt < 2; ++nt) {
            const int n = n0w + nt * 16 + l16;
#pragma unroll
            for (int r = 0; r < 4; ++r) {
                const int m = (mh * 4 + mt) * 16 + q * 4 + r;
                pp[(size_t)m * N + n] = f2h_(acc[mt][nt][r]);
            }
        }
}

// ---------------------------------------------------------------------------
__launch_bounds__(256)
__global__ void reduce_to_afrag(const u16* __restrict__ part, u16* __restrict__ out,
                                int SK) {
    const int idx = blockIdx.x * 256 + threadIdx.x;
    const int m = idx >> 9, c = idx & 511;
    float s[8] = {};
    for (int k = 0; k < SK; ++k)
        acc8(*(const uint4*)(part + (size_t)k * 524288 + (size_t)m * 4096 + c * 8), s);
    const int kb = c >> 2, qq = c & 3, mt = m >> 4, l16 = m & 15;
    u16 o8[8];
#pragma unroll
    for (int j = 0; j < 8; ++j) o8[j] = f2h_(s[j]);
    *(uint4*)(out + ((size_t)(kb * 8 + mt) * 64 + qq * 16 + l16) * 8) = *(const uint4*)o8;
}

__launch_bounds__(256)
__global__ void reduce_add_f32(const u16* __restrict__ part, const float* __restrict__ resin,
                               float* __restrict__ out, int SK) {
    const int idx = blockIdx.x * 256 + threadIdx.x;
    const size_t base = (size_t)idx * 8;
    float s[8];
    *(float4*)&s[0] = *(const float4*)(resin + base);
    *(float4*)&s[4] = *(const float4*)(resin + base + 4);
    for (int k = 0; k < SK; ++k)
        acc8(*(const uint4*)(part + (size_t)k * 524288 + base), s);
    *(float4*)(out + base)     = *(const float4*)&s[0];
    *(float4*)(out + base + 4) = *(const float4*)&s[4];
}

__launch_bounds__(256)
__global__ void silu_mul(const u16* __restrict__ part, u16* __restrict__ act, int SK) {
    const int idx = blockIdx.x * 256 + threadIdx.x;
    const int m = idx / 1376, c = idx - m * 1376;
    const int nb = c * 8;
    float g[8] = {}, u[8] = {};
    for (int k = 0; k < SK; ++k) {
        const size_t base = (size_t)k * 2818048 + (size_t)m * 22016 + nb;
        acc8(*(const uint4*)(part + base), g);
        acc8(*(const uint4*)(part + base + 11008), u);
    }
    const int kb = nb >> 5, qq = (nb >> 3) & 3, mt = m >> 4, l16 = m & 15;
    u16 o8[8];
#pragma unroll
    for (int j = 0; j < 8; ++j) {
        float a = g[j] / (1.f + __expf(-g[j])) * u[j];
        o8[j] = f2h_(a);
    }
    *(uint4*)(act + ((size_t)(kb * 8 + mt) * 64 + qq * 16 + l16) * 8) = *(const uint4*)o8;
}

// ---------------------------------------------------------------------------
extern "C" void kernel_launch(void* const* d_in, const int* in_sizes, int n_in,
                              void* d_out, int out_size, void* d_ws, size_t ws_size,
                              hipStream_t stream) {
    const float* x      = (const float*)d_in[0];
    const float* ln1_w  = (const float*)d_in[1];
    const float* ln2_w  = (const float*)d_in[2];
    const int*   qkv_qw = (const int*)d_in[3];
    const int*   qkv_qz = (const int*)d_in[4];
    const float* qkv_sc = (const float*)d_in[5];
    const int*   o_qw   = (const int*)d_in[6];
    const int*   o_qz   = (const int*)d_in[7];
    const float* o_sc   = (const float*)d_in[8];
    const int*   gu_qw  = (const int*)d_in[9];
    const int*   gu_qz  = (const int*)d_in[10];
    const float* gu_sc  = (const float*)d_in[11];
    const int*   dn_qw  = (const int*)d_in[12];
    const int*   dn_qz  = (const int*)d_in[13];
    const float* dn_sc  = (const float*)d_in[14];
    float* out = (float*)d_out;

    // ws layout (~31.3 MB; harness provides >= 70.8 MB, verified in round 3)
    char* ws = (char*)d_ws;
    u16*   pbuf = (u16*)(ws);                 // partials: max 22.5 MB (gu SK4)
    u32*   zsb  = (u32*)(ws + 22544384);      // 2.82 MB, reused per gemm
    u16*   act  = (u16*)(ws + 25362432);      // 2.75 MB fp16 (Afrag)
    float* res2 = (float*)(ws + 28180480);    // 2 MB fp32
    u16*   slot = (u16*)(ws + 30277632);      // 1 MB fp16 Afrag (h1/qb/h2)

    // h1 = rmsnorm(x, ln1) -> Afrag ; zs for qkv
    rmsnorm_k<<<128, 256, 0, stream>>>(x, ln1_w, slot);
    pack_zs<<<512, 256, 0, stream>>>(qkv_qz, qkv_sc, zsb, 1536, 12288, 4096, 131072);

    // q = h1 @ Wqkv[:, :4096]   (64 tiles x SK16, kchunk 256 -> 1024 blocks)
    gemm_awq<<<dim3(64, 16), 256, 0, stream>>>(slot, zsb, qkv_qw, pbuf,
                                               1536, 4096, 4096, 256);
    reduce_to_afrag<<<256, 256, 0, stream>>>(pbuf, slot, 16);
    pack_zs<<<512, 256, 0, stream>>>(o_qz, o_sc, zsb, 512, 4096, 4096, 131072);

    // attn = q @ Wo ; res2 = x + attn
    gemm_awq<<<dim3(64, 16), 256, 0, stream>>>(slot, zsb, o_qw, pbuf,
                                               512, 4096, 4096, 256);
    reduce_add_f32<<<256, 256, 0, stream>>>(pbuf, x, res2, 16);

    // h2 = rmsnorm(res2, ln2) -> Afrag ; zs for gu
    rmsnorm_k<<<128, 256, 0, stream>>>(res2, ln2_w, slot);
    pack_zs<<<2752, 256, 0, stream>>>(gu_qz, gu_sc, zsb, 2752, 22016, 22016, 704512);

    // gate_up = h2 @ Wgu   (344 tiles x SK4, kchunk 1024 -> 1376 blocks)
    gemm_awq<<<dim3(344, 4), 256, 0, stream>>>(slot, zsb, gu_qw, pbuf,
                                               2752, 22016, 4096, 1024);
    silu_mul<<<688, 256, 0, stream>>>(pbuf, act, 4);
    pack_zs<<<1376, 256, 0, stream>>>(dn_qz, dn_sc, zsb, 512, 4096, 4096, 352256);

    // down = act @ Wdn   (64 tiles x SK20, kchunk 576 -> 1280 blocks)
    gemm_awq<<<dim3(64, 20), 256, 0, stream>>>(act, zsb, dn_qw, pbuf,
                                               512, 4096, 11008, 576);
    reduce_add_f32<<<256, 256, 0, stream>>>(pbuf, res2, out, 20);
}

// Round 5
// 299.919 us; speedup vs baseline: 1.1324x; 1.0241x over previous
//
#include <hip/hip_runtime.h>

typedef unsigned int   u32;
typedef unsigned short u16;

typedef _Float16 h2  __attribute__((ext_vector_type(2)));
typedef _Float16 h8  __attribute__((ext_vector_type(8)));
typedef float    f32x4 __attribute__((ext_vector_type(4)));

#define M_TOK 128

__device__ __forceinline__ u16 f2h_(float f) {
    _Float16 h = (_Float16)f; return __builtin_bit_cast(u16, h);
}
__device__ __forceinline__ float h2f_(u16 b) {
    _Float16 h = __builtin_bit_cast(_Float16, b); return (float)h;
}
__device__ __forceinline__ void acc8(uint4 v, float* s) {
#pragma unroll
    for (int i = 0; i < 4; ++i) {
        u32 w = ((const u32*)&v)[i];
        s[2 * i]     += h2f_((u16)(w & 0xFFFF));
        s[2 * i + 1] += h2f_((u16)(w >> 16));
    }
}

// AWQ nibble order: n&7 = j sits at bit position SH[j]
__constant__ int SHC[8] = {0, 16, 4, 20, 8, 24, 12, 28};

// ---------------------------------------------------------------------------
// pack_zs: (qz, sc) -> zs[g][n] u32 { lo16: fp16(-(1024+z)), hi16: fp16(sc) }
// ---------------------------------------------------------------------------
__launch_bounds__(256)
__global__ void pack_zs(const int* __restrict__ qz, const float* __restrict__ sc,
                        u32* __restrict__ zs, int qws, int scs, int Ncols, int total) {
    const int idx = blockIdx.x * 256 + threadIdx.x;
    if (idx >= total) return;
    const int g = idx / Ncols, n = idx - g * Ncols;
    const u32 d = (u32)qz[(size_t)g * qws + (n >> 3)];
    const u32 zj = (d >> SHC[n & 7]) & 15u;
    const u32 mz = 0xE400u | zj;                    // fp16 -(1024+z)
    const u16 sh = f2h_(sc[(size_t)g * scs + n]);
    zs[(size_t)g * Ncols + n] = mz | ((u32)sh << 16);
}

// A-fragment-major layout: elem offset for logical (m, k):
//   kb=k/32, q=(k/8)&3, j=k&7, mt=m/16, l16=m&15
//   off = ((kb*8+mt)*64 + q*16 + l16)*8 + j    (fp16 elements)

// ---------------------------------------------------------------------------
// RMSNorm: one block per token row, fp32 in -> fp16 out in Afrag layout
// ---------------------------------------------------------------------------
__launch_bounds__(256)
__global__ void rmsnorm_k(const float* __restrict__ in, const float* __restrict__ w,
                          u16* __restrict__ out) {
    const int row = blockIdx.x;
    const float* x = in + (size_t)row * 4096;
    float ss = 0.f;
#pragma unroll
    for (int j = 0; j < 16; ++j) {
        float v = x[threadIdx.x + 256 * j];
        ss += v * v;
    }
#pragma unroll
    for (int off = 32; off > 0; off >>= 1) ss += __shfl_down(ss, off, 64);
    __shared__ float ws4[4];
    if ((threadIdx.x & 63) == 0) ws4[threadIdx.x >> 6] = ss;
    __syncthreads();
    float total = ws4[0] + ws4[1] + ws4[2] + ws4[3];
    float r = rsqrtf(total * (1.f / 4096.f) + 1e-6f);
    const int mt = row >> 4, l16 = row & 15;
#pragma unroll
    for (int c2 = 0; c2 < 2; ++c2) {
        int c = threadIdx.x * 2 + c2;
        int kb = c >> 2, qq = c & 3;
        u16 o8[8];
#pragma unroll
        for (int j = 0; j < 8; ++j) {
            int i = c * 8 + j;
            o8[j] = f2h_(x[i] * r * w[i]);
        }
        *(uint4*)(out + ((size_t)(kb * 8 + mt) * 64 + qq * 16 + l16) * 8) = *(const uint4*)o8;
    }
}

// ---------------------------------------------------------------------------
// AWQ GEMM. Wave tile 64m x 32n; block 128m x 64n (2 m-halves x 2 n-halves).
// The mh-pair waves {w, w+2} SHARE one 32n x 64k B tile in LDS, double-
// buffered: wave mh=0 dequants n-cols 0-15, mh=1 dequants 16-31 (each loads
// only its uint2 of raw qw -> no duplicate fetch, half the route/emit/write
// work of round 4). The per-step __syncthreads() orders cross-wave
// write(i+1 -> buf^1) vs read(i+1); reads of buf(i) complete before the
// barrier (lgkm drain), so one barrier per step suffices.
// __launch_bounds__(256,4): 4 waves/SIMD; grids ~4-5 blocks/CU; chunked XCD
// swizzle keeps adjacent n-tiles (same weight rows) on the same XCD L2.
// ---------------------------------------------------------------------------
__launch_bounds__(256, 4)
__global__ void gemm_awq(const u16* __restrict__ A, const u32* __restrict__ zs,
                         const int* __restrict__ qw, u16* __restrict__ part,
                         int qws, int N, int K, int kchunk) {
    __shared__ __align__(16) char ldsB[4 * 4608];   // [nhalf][2 bufs] 32n x 64k

    const int tid = threadIdx.x, w = tid >> 6, lane = tid & 63;
    const int q = lane >> 4, l16 = lane & 15;
    const int mh = w >> 1, nh = w & 1;
    // chunked XCD swizzle (gridDim.x is a multiple of 8 for all call sites)
    const int bx = (blockIdx.x & 7) * (gridDim.x >> 3) + (blockIdx.x >> 3);
    const int n0w = bx * 64 + nh * 32;               // 32n strip of this wave
    const int pc0 = n0w >> 3;
    const int kp = lane & 31, h = lane >> 5;
    const int sk = blockIdx.y, kc0 = sk * kchunk, kend = min(kc0 + kchunk, K);

    char* buf0 = ldsB + nh * 9216;                   // shared by the mh-pair
    char* buf1 = buf0 + 4608;
    const u16* Ala = A + lane * 8;
    const int* qwp = qw + pc0 + mh * 2;              // this wave's 16n of raw qw
    const u32* zsP = zs + n0w + mh * 16 + h * 8;     // this wave's zs octets
    const int nbase = mh * 16 + h * 8;               // LDS n-column base

    f32x4 acc[4][2] = {};
    uint4 z0, z1;                    // current group's packed (mz, sc), 8 n

    auto ldraw = [&](int k0) -> uint2 {
        return *(const uint2*)(qwp + (size_t)(k0 + lane) * qws);
    };
    auto loadzs = [&](int g) {
        z0 = *(const uint4*)(zsP + (size_t)g * N);
        z1 = *(const uint4*)(zsP + (size_t)g * N + 4);
    };
    // dequant this wave's 16n half of a 64k tile into buf
    auto dq = [&](uint2 rv, char* buf) {
        const int i0 = kp * 8, i1 = i0 + 4;
        int b00 = __builtin_amdgcn_ds_bpermute(i0, (int)rv.x);
        int b10 = __builtin_amdgcn_ds_bpermute(i0, (int)rv.y);
        int b01 = __builtin_amdgcn_ds_bpermute(i1, (int)rv.x);
        int b11 = __builtin_amdgcn_ds_bpermute(i1, (int)rv.y);
        u32 w0 = (u32)(h ? b10 : b00);               // row 2kp   dword
        u32 w1 = (u32)(h ? b11 : b01);               // row 2kp+1 dword
        char* bb = buf + kp * 4 + nbase * 144;
        u32 w0s = w0 >> 4, w1s = w1 >> 4;
        auto em = [&](int j, u32 a0, u32 a1, int b, u32 zsj) {
            h2 mz = __builtin_bit_cast(h2, __builtin_amdgcn_perm(zsj, zsj, 0x01000100u));
            h2 s2 = __builtin_bit_cast(h2, __builtin_amdgcn_perm(zsj, zsj, 0x03020302u));
            u32 t = __builtin_amdgcn_perm(a1, a0, (u32)(b | ((b + 4) << 16)));
            u32 u = (t & 0x000F000Fu) | 0x64006400u;
            h2 v = (__builtin_bit_cast(h2, u) + mz) * s2;
            *(u32*)(bb + j * 144) = __builtin_bit_cast(u32, v);
        };
        em(0, w0, w1, 0, z0.x);  em(4, w0, w1, 1, z1.x);
        em(1, w0, w1, 2, z0.y);  em(5, w0, w1, 3, z1.y);
        em(2, w0s, w1s, 0, z0.z); em(6, w0s, w1s, 1, z1.z);
        em(3, w0s, w1s, 2, z0.w); em(7, w0s, w1s, 3, z1.w);
    };
    auto lda = [&](int k, uint4(&dst)[2][4]) {
        const int kb = k >> 5;
#pragma unroll
        for (int c = 0; c < 2; ++c)
#pragma unroll
            for (int mt = 0; mt < 4; ++mt)
                dst[c][mt] = *(const uint4*)(Ala + (size_t)((kb + c) * 8 + mh * 4 + mt) * 512);
    };

    uint2 rv_n = {0, 0};

    // ---- prologue: each wave dequants its half of B(0) into buf0 ----
    loadzs(kc0 >> 7);
    uint2 rv0 = ldraw(kc0);
    if (kc0 + 64 < kend) rv_n = ldraw(kc0 + 64);
    dq(rv0, buf0);
    if (((kc0 + 64) & 127) == 0 && kc0 + 64 < kend)
        loadzs((kc0 + 64) >> 7);        // mid-group chunk start (dn)

    // ---- main loop ----
    char* cur = buf0; char* nxt = buf1;
    for (int k0 = kc0; k0 < kend; k0 += 64) {
        __syncthreads();    // orders pair writes(B(i)) before reads(B(i))
        const bool kn1 = (k0 + 64) < kend, kn2 = (k0 + 128) < kend;
        uint4 af[2][4];
        lda(k0, af);                                  // A(i), consumed by MFMA below
        uint4 bv[2][2];
#pragma unroll
        for (int c = 0; c < 2; ++c)
#pragma unroll
            for (int nt = 0; nt < 2; ++nt)
                bv[c][nt] = *(const uint4*)(cur + (nt * 16 + l16) * 144 + c * 64 + q * 16);
        uint2 rv_f = {0, 0};
        if (kn2) rv_f = ldraw(k0 + 128);              // raw(i+2)
        if (kn1) dq(rv_n, nxt);                       // dequant half of B(i+1)
        if (kn2 && (((k0 + 128) & 127) == 0))         // zs(group+1), used next step
            loadzs((k0 + 128) >> 7);
        // MFMA(i)
#pragma unroll
        for (int c = 0; c < 2; ++c)
#pragma unroll
            for (int mt = 0; mt < 4; ++mt)
#pragma unroll
                for (int nt = 0; nt < 2; ++nt)
                    acc[mt][nt] = __builtin_amdgcn_mfma_f32_16x16x32_f16(
                        __builtin_bit_cast(h8, af[c][mt]),
                        __builtin_bit_cast(h8, bv[c][nt]),
                        acc[mt][nt], 0, 0, 0);
        rv_n = rv_f;
        char* t = cur; cur = nxt; nxt = t;
    }

    // ---- epilogue: fp16 partial store ----
    u16* pp = part + (size_t)sk * M_TOK * N;
#pragma unroll
    for (int mt = 0; mt < 4; ++mt)
#pragma unroll
        for (int nt = 0; nt < 2; ++nt) {
            const int n = n0w + nt * 16 + l16;
#pragma unroll
            for (int r = 0; r < 4; ++r) {
                const int m = (mh * 4 + mt) * 16 + q * 4 + r;
                pp[(size_t)m * N + n] = f2h_(acc[mt][nt][r]);
            }
        }
}

// ---------------------------------------------------------------------------
__launch_bounds__(256)
__global__ void reduce_to_afrag(const u16* __restrict__ part, u16* __restrict__ out,
                                int SK) {
    const int idx = blockIdx.x * 256 + threadIdx.x;
    const int m = idx >> 9, c = idx & 511;
    float s[8] = {};
    for (int k = 0; k < SK; ++k)
        acc8(*(const uint4*)(part + (size_t)k * 524288 + (size_t)m * 4096 + c * 8), s);
    const int kb = c >> 2, qq = c & 3, mt = m >> 4, l16 = m & 15;
    u16 o8[8];
#pragma unroll
    for (int j = 0; j < 8; ++j) o8[j] = f2h_(s[j]);
    *(uint4*)(out + ((size_t)(kb * 8 + mt) * 64 + qq * 16 + l16) * 8) = *(const uint4*)o8;
}

__launch_bounds__(256)
__global__ void reduce_add_f32(const u16* __restrict__ part, const float* __restrict__ resin,
                               float* __restrict__ out, int SK) {
    const int idx = blockIdx.x * 256 + threadIdx.x;
    const size_t base = (size_t)idx * 8;
    float s[8];
    *(float4*)&s[0] = *(const float4*)(resin + base);
    *(float4*)&s[4] = *(const float4*)(resin + base + 4);
    for (int k = 0; k < SK; ++k)
        acc8(*(const uint4*)(part + (size_t)k * 524288 + base), s);
    *(float4*)(out + base)     = *(const float4*)&s[0];
    *(float4*)(out + base + 4) = *(const float4*)&s[4];
}

__launch_bounds__(256)
__global__ void silu_mul(const u16* __restrict__ part, u16* __restrict__ act, int SK) {
    const int idx = blockIdx.x * 256 + threadIdx.x;
    const int m = idx / 1376, c = idx - m * 1376;
    const int nb = c * 8;
    float g[8] = {}, u[8] = {};
    for (int k = 0; k < SK; ++k) {
        const size_t base = (size_t)k * 2818048 + (size_t)m * 22016 + nb;
        acc8(*(const uint4*)(part + base), g);
        acc8(*(const uint4*)(part + base + 11008), u);
    }
    const int kb = nb >> 5, qq = (nb >> 3) & 3, mt = m >> 4, l16 = m & 15;
    u16 o8[8];
#pragma unroll
    for (int j = 0; j < 8; ++j) {
        float a = g[j] / (1.f + __expf(-g[j])) * u[j];
        o8[j] = f2h_(a);
    }
    *(uint4*)(act + ((size_t)(kb * 8 + mt) * 64 + qq * 16 + l16) * 8) = *(const uint4*)o8;
}

// ---------------------------------------------------------------------------
extern "C" void kernel_launch(void* const* d_in, const int* in_sizes, int n_in,
                              void* d_out, int out_size, void* d_ws, size_t ws_size,
                              hipStream_t stream) {
    const float* x      = (const float*)d_in[0];
    const float* ln1_w  = (const float*)d_in[1];
    const float* ln2_w  = (const float*)d_in[2];
    const int*   qkv_qw = (const int*)d_in[3];
    const int*   qkv_qz = (const int*)d_in[4];
    const float* qkv_sc = (const float*)d_in[5];
    const int*   o_qw   = (const int*)d_in[6];
    const int*   o_qz   = (const int*)d_in[7];
    const float* o_sc   = (const float*)d_in[8];
    const int*   gu_qw  = (const int*)d_in[9];
    const int*   gu_qz  = (const int*)d_in[10];
    const float* gu_sc  = (const float*)d_in[11];
    const int*   dn_qw  = (const int*)d_in[12];
    const int*   dn_qz  = (const int*)d_in[13];
    const float* dn_sc  = (const float*)d_in[14];
    float* out = (float*)d_out;

    // ws layout (~31.3 MB)
    char* ws = (char*)d_ws;
    u16*   pbuf = (u16*)(ws);                 // partials: max 22.5 MB (gu SK4)
    u32*   zsb  = (u32*)(ws + 22544384);      // 2.82 MB, reused per gemm
    u16*   act  = (u16*)(ws + 25362432);      // 2.75 MB fp16 (Afrag)
    float* res2 = (float*)(ws + 28180480);    // 2 MB fp32
    u16*   slot = (u16*)(ws + 30277632);      // 1 MB fp16 Afrag (h1/qb/h2)

    // h1 = rmsnorm(x, ln1) -> Afrag ; zs for qkv
    rmsnorm_k<<<128, 256, 0, stream>>>(x, ln1_w, slot);
    pack_zs<<<512, 256, 0, stream>>>(qkv_qz, qkv_sc, zsb, 1536, 12288, 4096, 131072);

    // q = h1 @ Wqkv[:, :4096]   (64 tiles x SK16, kchunk 256 -> 1024 blocks)
    gemm_awq<<<dim3(64, 16), 256, 0, stream>>>(slot, zsb, qkv_qw, pbuf,
                                               1536, 4096, 4096, 256);
    reduce_to_afrag<<<256, 256, 0, stream>>>(pbuf, slot, 16);
    pack_zs<<<512, 256, 0, stream>>>(o_qz, o_sc, zsb, 512, 4096, 4096, 131072);

    // attn = q @ Wo ; res2 = x + attn
    gemm_awq<<<dim3(64, 16), 256, 0, stream>>>(slot, zsb, o_qw, pbuf,
                                               512, 4096, 4096, 256);
    reduce_add_f32<<<256, 256, 0, stream>>>(pbuf, x, res2, 16);

    // h2 = rmsnorm(res2, ln2) -> Afrag ; zs for gu
    rmsnorm_k<<<128, 256, 0, stream>>>(res2, ln2_w, slot);
    pack_zs<<<2752, 256, 0, stream>>>(gu_qz, gu_sc, zsb, 2752, 22016, 22016, 704512);

    // gate_up = h2 @ Wgu   (344 tiles x SK4, kchunk 1024 -> 1376 blocks)
    gemm_awq<<<dim3(344, 4), 256, 0, stream>>>(slot, zsb, gu_qw, pbuf,
                                               2752, 22016, 4096, 1024);
    silu_mul<<<688, 256, 0, stream>>>(pbuf, act, 4);
    pack_zs<<<1376, 256, 0, stream>>>(dn_qz, dn_sc, zsb, 512, 4096, 4096, 352256);

    // down = act @ Wdn   (64 tiles x SK20, kchunk 576 -> 1280 blocks)
    gemm_awq<<<dim3(64, 20), 256, 0, stream>>>(act, zsb, dn_qw, pbuf,
                                               512, 4096, 11008, 576);
    reduce_add_f32<<<256, 256, 0, stream>>>(pbuf, res2, out, 20);
}